// Round 19
// baseline (197.065 us; speedup 1.0000x reference)
//
#include <hip/hip_runtime.h>

#define Bv 8
#define Sv 1024
#define Dv 768
#define Hv 12
#define DKv 64
#define Mv (Bv*Sv)          // 8192
#define NQKV (3*Hv*DKv)     // 2304
#define NQK (2*Hv*DKv)      // 1536

typedef __attribute__((ext_vector_type(8))) short short8;
typedef __attribute__((ext_vector_type(4))) short short4v;
typedef __attribute__((ext_vector_type(4))) float f32x4;

__device__ __forceinline__ short f2bf(float f) {
    unsigned u = __builtin_bit_cast(unsigned, f);
    u += 0x7fffu + ((u >> 16) & 1u);
    return (short)(u >> 16);
}
__device__ __forceinline__ float bf2f(short h) {
    return __builtin_bit_cast(float, (unsigned)(unsigned short)h << 16);
}

__device__ __forceinline__ f32x4 mfma16(short8 a, short8 b, f32x4 c) {
    return __builtin_amdgcn_mfma_f32_16x16x32_bf16(a, b, c, 0, 0, 0);
}

__device__ __forceinline__ void gload16(const short* g, const short* l) {
    __builtin_amdgcn_global_load_lds(
        (const __attribute__((address_space(1))) unsigned int*)g,
        (__attribute__((address_space(3))) unsigned int*)(short*)l, 16, 0, 0);
}

// ---------------- fused prep: split x | pack Wqkv hi/lo (Wq pre-scaled 1/8) | W^T ----------------
__global__ __launch_bounds__(256) void prep_kernel(const float* __restrict__ x,
                                                   const float* __restrict__ Wq,
                                                   const float* __restrict__ Wk,
                                                   const float* __restrict__ Wv,
                                                   const float* __restrict__ W,
                                                   short* __restrict__ xh, short* __restrict__ xl,
                                                   short* __restrict__ Wh, short* __restrict__ Wl,
                                                   short* __restrict__ W2T) {
    __shared__ float lds[64][65];
    int bid = blockIdx.x;
    int t = threadIdx.x;
    if (bid < 3072) {
        int idx = bid * 256 + t;
        const float4* f = (const float4*)x + (size_t)idx * 2;
        float4 a = f[0], b = f[1];
        float v[8] = {a.x,a.y,a.z,a.w,b.x,b.y,b.z,b.w};
        short8 oh, ol;
#pragma unroll
        for (int k = 0; k < 8; k++) {
            short hi = f2bf(v[k]);
            oh[k] = hi;
            ol[k] = f2bf(v[k] - bf2f(hi));
        }
        *((short8*)xh + idx) = oh;
        *((short8*)xl + idx) = ol;
    } else if (bid < 3504) {
        int idx = bid - 3072;
        int dt = idx % 12, h = (idx / 12) % 12, p = idx / 144;
        const float* S = (p == 0 ? Wq : (p == 1 ? Wk : Wv)) + (size_t)h * Dv * DKv;
        float sc = (p == 0) ? 0.125f : 1.0f;
        int d0 = dt * 64;
#pragma unroll
        for (int i = 0; i < 4; i++) {
            int v = t + i * 256;
            int r = v >> 4, c4 = v & 15;
            float4 f = *(const float4*)&S[(size_t)(d0 + r) * DKv + c4 * 4];
            lds[r][c4*4+0] = f.x; lds[r][c4*4+1] = f.y; lds[r][c4*4+2] = f.z; lds[r][c4*4+3] = f.w;
        }
        __syncthreads();
#pragma unroll
        for (int i = 0; i < 2; i++) {
            int v = t + i * 256;
            int kk = v >> 3, dl0 = (v & 7) * 8;
            short8 oh, ol;
#pragma unroll
            for (int k = 0; k < 8; k++) {
                float f = lds[dl0 + k][kk] * sc;
                short hi = f2bf(f);
                oh[k] = hi;
                ol[k] = f2bf(f - bf2f(hi));
            }
            size_t base = (size_t)(p*768 + h*64 + kk) * Dv + d0 + dl0;
            *(short8*)&Wh[base] = oh;
            if (p < 2) *(short8*)&Wl[base] = ol;
        }
    } else {
        int idx = bid - 3504;
        int c0 = (idx % 12) * 64, r0 = (idx / 12) * 64;
#pragma unroll
        for (int i = 0; i < 4; i++) {
            int v = t + i * 256;
            int r = v >> 4, c4 = v & 15;
            float4 f = *(const float4*)&W[(size_t)(r0 + r) * Dv + c0 + c4 * 4];
            lds[r][c4*4+0] = f.x; lds[r][c4*4+1] = f.y; lds[r][c4*4+2] = f.z; lds[r][c4*4+3] = f.w;
        }
        __syncthreads();
#pragma unroll
        for (int i = 0; i < 2; i++) {
            int v = t + i * 256;
            int oc = v >> 3, rl0 = (v & 7) * 8;
            short8 o;
#pragma unroll
            for (int k = 0; k < 8; k++) o[k] = f2bf(lds[rl0 + k][oc]);
            *(short8*)&W2T[(size_t)(c0 + oc) * Dv + r0 + rl0] = o;
        }
    }
}

// XCD-affinity block swizzle for 1D grids over (x:NX, y:64)
__device__ __forceinline__ void swz_xy(int n, int& xbl, int& ybl) {
    int cx = n & 7, k = n >> 3;
    ybl = cx + 8 * (k & 7);
    xbl = k >> 3;
}

// ---------------- gemm_qk: merged-segment split GEMM (768 blocks = 3/CU exact) ----------------
// phase 1 (t<24): stage {xh,Wh,Wl} (6 loads), 32 MFMA; phase 2: stage {xl,Wh}, 16 MFMA.
__global__ __launch_bounds__(256, 3) void gemm_qk_kernel(const short* __restrict__ xh,
                                                         const short* __restrict__ xl,
                                                         const short* __restrict__ Wh,
                                                         const short* __restrict__ Wl,
                                                         short* __restrict__ QKVh,
                                                         short* __restrict__ QKVl) {
    int xbl, ybl;
    swz_xy(blockIdx.x, xbl, ybl);          // xbl 0..11, ybl 0..63
    int m0 = ybl * 128, n0 = xbl * 128;
    const int KT = 48;
    __shared__ __align__(16) short lA[2][4096];
    __shared__ __align__(16) short lBh[2][4096];
    __shared__ __align__(16) short lBl[2][4096];
    int tid = threadIdx.x, lane = tid & 63, w = tid >> 6;
    int wr = w >> 1, wc = w & 1;
    int li = lane & 15, g = lane >> 4;
    f32x4 zero = {0.f, 0.f, 0.f, 0.f};
    f32x4 acc[4][4];
#pragma unroll
    for (int i = 0; i < 4; i++)
#pragma unroll
        for (int j = 0; j < 4; j++) acc[i][j] = zero;

    int e0 = tid * 8;
    int sr0 = e0 >> 5;
    int sc0 = ((e0 >> 3) & 3) ^ ((sr0 >> 1) & 3);
    int sr1 = sr0 + 64;
    int sc1 = ((e0 >> 3) & 3) ^ ((sr1 >> 1) & 3);

    auto stage = [&](int t, int buf) {
        if (t < 24) {
            int kk = t * 32;
            gload16(xh + (size_t)(m0 + sr0) * Dv + kk + sc0 * 8, &lA[buf][w * 512]);
            gload16(Wh + (size_t)(n0 + sr0) * Dv + kk + sc0 * 8, &lBh[buf][w * 512]);
            gload16(Wl + (size_t)(n0 + sr0) * Dv + kk + sc0 * 8, &lBl[buf][w * 512]);
            gload16(xh + (size_t)(m0 + sr1) * Dv + kk + sc1 * 8, &lA[buf][2048 + w * 512]);
            gload16(Wh + (size_t)(n0 + sr1) * Dv + kk + sc1 * 8, &lBh[buf][2048 + w * 512]);
            gload16(Wl + (size_t)(n0 + sr1) * Dv + kk + sc1 * 8, &lBl[buf][2048 + w * 512]);
        } else {
            int kk = (t - 24) * 32;
            gload16(xl + (size_t)(m0 + sr0) * Dv + kk + sc0 * 8, &lA[buf][w * 512]);
            gload16(Wh + (size_t)(n0 + sr0) * Dv + kk + sc0 * 8, &lBh[buf][w * 512]);
            gload16(xl + (size_t)(m0 + sr1) * Dv + kk + sc1 * 8, &lA[buf][2048 + w * 512]);
            gload16(Wh + (size_t)(n0 + sr1) * Dv + kk + sc1 * 8, &lBh[buf][2048 + w * 512]);
        }
    };

    stage(0, 0);
    stage(1, 1);

    for (int t = 0; t < KT; t++) {
        int cur = t & 1;
        if (t + 1 < KT) {
            if (t + 1 < 24) asm volatile("s_waitcnt vmcnt(6)" ::: "memory");
            else            asm volatile("s_waitcnt vmcnt(4)" ::: "memory");
        } else {
            asm volatile("s_waitcnt vmcnt(0)" ::: "memory");
        }
        __builtin_amdgcn_s_barrier();
        __builtin_amdgcn_sched_barrier(0);
        bool tri = (t < 24);
        short8 a[4], bbh[4], bbl[4];
#pragma unroll
        for (int mi = 0; mi < 4; mi++) {
            int row = wr*64 + mi*16 + li;
            a[mi] = *(const short8*)&lA[cur][row * 32 + ((g ^ ((row >> 1) & 3)) << 3)];
        }
#pragma unroll
        for (int ni = 0; ni < 4; ni++) {
            int row = wc*64 + ni*16 + li;
            bbh[ni] = *(const short8*)&lBh[cur][row * 32 + ((g ^ ((row >> 1) & 3)) << 3)];
        }
        if (tri) {
#pragma unroll
            for (int ni = 0; ni < 4; ni++) {
                int row = wc*64 + ni*16 + li;
                bbl[ni] = *(const short8*)&lBl[cur][row * 32 + ((g ^ ((row >> 1) & 3)) << 3)];
            }
        }
#pragma unroll
        for (int mi = 0; mi < 4; mi++)
#pragma unroll
            for (int ni = 0; ni < 4; ni++)
                acc[mi][ni] = mfma16(a[mi], bbh[ni], acc[mi][ni]);
        if (tri) {
#pragma unroll
            for (int mi = 0; mi < 4; mi++)
#pragma unroll
                for (int ni = 0; ni < 4; ni++)
                    acc[mi][ni] = mfma16(a[mi], bbl[ni], acc[mi][ni]);
        }
        __builtin_amdgcn_sched_barrier(0);
        __builtin_amdgcn_s_barrier();
        __builtin_amdgcn_sched_barrier(0);
        if (t + 2 < KT) stage(t + 2, cur);
    }
#pragma unroll
    for (int mi = 0; mi < 4; mi++)
#pragma unroll
        for (int ni = 0; ni < 4; ni++)
#pragma unroll
            for (int j = 0; j < 4; j++) {
                int row = m0 + wr*64 + mi*16 + g*4 + j;
                int col = n0 + wc*64 + ni*16 + li;
                float v = acc[mi][ni][j];
                short hi = f2bf(v);
                QKVh[(size_t)row * NQKV + col] = hi;
                QKVl[(size_t)row * NQK + col] = f2bf(v - bf2f(hi));
            }
}

// ---------------- gemm_v: plain dual loop (384 blocks, 32KB LDS), launched just before attn ----------------
__global__ __launch_bounds__(256, 4) void gemm_v_kernel(const short* __restrict__ xh,
                                                        const short* __restrict__ Wh,
                                                        short* __restrict__ Vt) {
    int xbl, ybl;
    swz_xy(blockIdx.x, xbl, ybl);          // xbl 0..5, ybl 0..63
    int m0 = ybl * 128, n0 = NQK + xbl * 128;
    __shared__ __align__(16) short lA[2][4096];
    __shared__ __align__(16) short lB[2][4096];
    int tid = threadIdx.x, lane = tid & 63, w = tid >> 6;
    int wr = w >> 1, wc = w & 1;
    int li = lane & 15, g = lane >> 4;
    f32x4 zero = {0.f, 0.f, 0.f, 0.f};
    f32x4 acc[4][4];
#pragma unroll
    for (int i = 0; i < 4; i++)
#pragma unroll
        for (int j = 0; j < 4; j++) acc[i][j] = zero;

    int e0 = tid * 8;
    int sr0 = e0 >> 5;
    int sc0 = ((e0 >> 3) & 3) ^ ((sr0 >> 1) & 3);
    int sr1 = sr0 + 64;
    int sc1 = ((e0 >> 3) & 3) ^ ((sr1 >> 1) & 3);

    auto stage = [&](int t, int buf) {
        int kk = t * 32;
        gload16(xh + (size_t)(m0 + sr0) * Dv + kk + sc0 * 8, &lA[buf][w * 512]);
        gload16(Wh + (size_t)(n0 + sr0) * Dv + kk + sc0 * 8, &lB[buf][w * 512]);
        gload16(xh + (size_t)(m0 + sr1) * Dv + kk + sc1 * 8, &lA[buf][2048 + w * 512]);
        gload16(Wh + (size_t)(n0 + sr1) * Dv + kk + sc1 * 8, &lB[buf][2048 + w * 512]);
    };

    stage(0, 0);
    stage(1, 1);

    for (int t = 0; t < 24; t++) {
        int cur = t & 1;
        if (t + 1 < 24) asm volatile("s_waitcnt vmcnt(4)" ::: "memory");
        else            asm volatile("s_waitcnt vmcnt(0)" ::: "memory");
        __builtin_amdgcn_s_barrier();
        __builtin_amdgcn_sched_barrier(0);
        short8 a[4], bb[4];
#pragma unroll
        for (int mi = 0; mi < 4; mi++) {
            int row = wr*64 + mi*16 + li;
            a[mi] = *(const short8*)&lA[cur][row * 32 + ((g ^ ((row >> 1) & 3)) << 3)];
        }
#pragma unroll
        for (int ni = 0; ni < 4; ni++) {
            int row = wc*64 + ni*16 + li;
            bb[ni] = *(const short8*)&lB[cur][row * 32 + ((g ^ ((row >> 1) & 3)) << 3)];
        }
#pragma unroll
        for (int mi = 0; mi < 4; mi++)
#pragma unroll
            for (int ni = 0; ni < 4; ni++)
                acc[mi][ni] = mfma16(a[mi], bb[ni], acc[mi][ni]);
        __builtin_amdgcn_sched_barrier(0);
        __builtin_amdgcn_s_barrier();
        __builtin_amdgcn_sched_barrier(0);
        if (t + 2 < 24) stage(t + 2, cur);
    }
#pragma unroll
    for (int mi = 0; mi < 4; mi++)
#pragma unroll
        for (int ni = 0; ni < 4; ni++) {
            int vcol = n0 + wc*64 + ni*16 + li - NQK;     // 0..767
            int h = vcol >> 6, dk = vcol & 63;
            int row0 = m0 + wr*64 + mi*16 + g*4;
            int b = row0 >> 10, s0 = row0 & 1023;
            short4v v4;
            v4[0] = f2bf(acc[mi][ni][0]); v4[1] = f2bf(acc[mi][ni][1]);
            v4[2] = f2bf(acc[mi][ni][2]); v4[3] = f2bf(acc[mi][ni][3]);
            *(short4v*)&Vt[(size_t)((b*Hv + h)*64 + dk) * Sv + s0] = v4;
        }
}

// ---------------- GEMM2: out(f32) = Zb @ W2T^T, counted-vmcnt loop ----------------
__global__ __launch_bounds__(256, 4) void gemm2_kernel(const short* __restrict__ A,
                                                       const short* __restrict__ Bt,
                                                       float* __restrict__ C) {
    int xbl, ybl;
    swz_xy(blockIdx.x, xbl, ybl);
    int m0 = ybl * 128, n0 = xbl * 128;
    __shared__ __align__(16) short lA[2][4096];
    __shared__ __align__(16) short lB[2][4096];
    int tid = threadIdx.x, lane = tid & 63, w = tid >> 6;
    int wr = w >> 1, wc = w & 1;
    int li = lane & 15, g = lane >> 4;
    f32x4 zero = {0.f, 0.f, 0.f, 0.f};
    f32x4 acc[4][4];
#pragma unroll
    for (int i = 0; i < 4; i++)
#pragma unroll
        for (int j = 0; j < 4; j++) acc[i][j] = zero;

    int e0 = tid * 8;
    int sr0 = e0 >> 5;
    int sc0 = ((e0 >> 3) & 3) ^ ((sr0 >> 1) & 3);
    int sr1 = sr0 + 64;
    int sc1 = ((e0 >> 3) & 3) ^ ((sr1 >> 1) & 3);

    auto stage = [&](int t, int buf) {
        int kk = t * 32;
        gload16(A  + (size_t)(m0 + sr0) * Dv + kk + sc0 * 8, &lA[buf][w * 512]);
        gload16(Bt + (size_t)(n0 + sr0) * Dv + kk + sc0 * 8, &lB[buf][w * 512]);
        gload16(A  + (size_t)(m0 + sr1) * Dv + kk + sc1 * 8, &lA[buf][2048 + w * 512]);
        gload16(Bt + (size_t)(n0 + sr1) * Dv + kk + sc1 * 8, &lB[buf][2048 + w * 512]);
    };

    stage(0, 0);
    stage(1, 1);

    for (int t = 0; t < 24; t++) {
        int cur = t & 1;
        if (t + 1 < 24) asm volatile("s_waitcnt vmcnt(4)" ::: "memory");
        else            asm volatile("s_waitcnt vmcnt(0)" ::: "memory");
        __builtin_amdgcn_s_barrier();
        __builtin_amdgcn_sched_barrier(0);
        short8 a[4], bb[4];
#pragma unroll
        for (int mi = 0; mi < 4; mi++) {
            int row = wr*64 + mi*16 + li;
            a[mi] = *(const short8*)&lA[cur][row * 32 + ((g ^ ((row >> 1) & 3)) << 3)];
        }
#pragma unroll
        for (int ni = 0; ni < 4; ni++) {
            int row = wc*64 + ni*16 + li;
            bb[ni] = *(const short8*)&lB[cur][row * 32 + ((g ^ ((row >> 1) & 3)) << 3)];
        }
#pragma unroll
        for (int mi = 0; mi < 4; mi++)
#pragma unroll
            for (int ni = 0; ni < 4; ni++)
                acc[mi][ni] = mfma16(a[mi], bb[ni], acc[mi][ni]);
        __builtin_amdgcn_sched_barrier(0);
        __builtin_amdgcn_s_barrier();
        __builtin_amdgcn_sched_barrier(0);
        if (t + 2 < 24) stage(t + 2, cur);
    }
#pragma unroll
    for (int mi = 0; mi < 4; mi++)
#pragma unroll
        for (int ni = 0; ni < 4; ni++)
#pragma unroll
            for (int j = 0; j < 4; j++) {
                int row = m0 + wr*64 + mi*16 + g*4 + j;
                int col = n0 + wc*64 + ni*16 + li;
                C[(size_t)row * Dv + col] = acc[mi][ni][j];
            }
}

// ---------------- flash attention (round-15 exact: (512,6), no spills) ----------------
__global__ __launch_bounds__(512, 6) void attn_kernel(const short* __restrict__ QKVh,
                                                      const short* __restrict__ QKVl,
                                                      const short* __restrict__ Vt,
                                                      short* __restrict__ Z) {
    int n = blockIdx.x;
    int j2 = n >> 3;
    int bh = (n & 7) + 8 * (j2 >> 3);
    int qb = j2 & 7;
    int b = bh / Hv, h = bh % Hv;
    int tid = threadIdx.x, lane = tid & 63, w = tid >> 6;
    int li = lane & 15, g = lane >> 4;

    __shared__ __align__(16) short Kh[64 * 64];
    __shared__ __align__(16) short Kl[64 * 64];
    __shared__ __align__(16) short Vs[64 * 64];
    __shared__ __align__(16) short P[8][1024];
    char* Pw = (char*)&P[w][0];
    const char* Khc = (const char*)Kh;
    const char* Klc = (const char*)Kl;
    const char* Vsc = (const char*)Vs;

    int qr0 = qb * 128 + w * 16;
    const short* qhr = QKVh + (size_t)(b*Sv + qr0 + li) * NQKV + h * DKv;
    const short* qlr = QKVl + (size_t)(b*Sv + qr0 + li) * NQK  + h * DKv;
    short8 qh0 = *(const short8*)(qhr + g * 8);
    short8 qh1 = *(const short8*)(qhr + 32 + g * 8);
    short8 ql0 = *(const short8*)(qlr + g * 8);
    short8 ql1 = *(const short8*)(qlr + 32 + g * 8);

    const short* Khb = QKVh + (size_t)(b*Sv) * NQKV + Hv*DKv + h*DKv;
    const short* Klb = QKVl + (size_t)(b*Sv) * NQK  + Hv*DKv + h*DKv;
    const short* Vbase = Vt + (size_t)(bh * 64) * Sv;

    int srow = w * 8 + (lane >> 3);
    int scs  = (lane & 7) ^ (srow & 7);

    float mm = -1e30f, ll = 0.f;
    f32x4 zero = {0.f, 0.f, 0.f, 0.f};
    f32x4 acc[4];
#pragma unroll
    for (int ni = 0; ni < 4; ni++) acc[ni] = zero;

    for (int t = 0; t < 16; t++) {
        int t0 = t * 64;
        gload16(Khb + (size_t)(t0 + srow) * NQKV + scs * 8, &Kh[w * 512]);
        gload16(Klb + (size_t)(t0 + srow) * NQK  + scs * 8, &Kl[w * 512]);
        gload16(Vbase + (size_t)srow * Sv + t0 + scs * 8,   &Vs[w * 512]);
        __syncthreads();

        f32x4 s[4];
#pragma unroll
        for (int tn = 0; tn < 4; tn++) {
            int row = tn * 16 + li;
            int rb = row * 128, rs = (row & 7) << 4;
            short8 kh0 = *(const short8*)(Khc + rb + ((g << 4) ^ rs));
            short8 kh1 = *(const short8*)(Khc + rb + ((64 + (g << 4)) ^ rs));
            short8 kl0 = *(const short8*)(Klc + rb + ((g << 4) ^ rs));
            short8 kl1 = *(const short8*)(Klc + rb + ((64 + (g << 4)) ^ rs));
            f32x4 z = mfma16(kh0, qh0, zero);
            z = mfma16(kh1, qh1, z);
            z = mfma16(kl0, qh0, z);
            z = mfma16(kl1, qh1, z);
            z = mfma16(kh0, ql0, z);
            z = mfma16(kh1, ql1, z);
            s[tn] = z;
        }
        float rm = s[0][0];
#pragma unroll
        for (int tn = 0; tn < 4; tn++)
#pragma unroll
            for (int jj = 0; jj < 4; jj++) rm = fmaxf(rm, s[tn][jj]);
        rm = fmaxf(rm, __shfl_xor(rm, 16));
        rm = fmaxf(rm, __shfl_xor(rm, 32));
        float mn = fmaxf(mm, rm);
        float sfu = __expf(mm - mn);
        float p[4][4];
        float rs2 = 0.f;
#pragma unroll
        for (int tn = 0; tn < 4; tn++)
#pragma unroll
            for (int jj = 0; jj < 4; jj++) { p[tn][jj] = __expf(s[tn][jj] - mn); rs2 += p[tn][jj]; }
        rs2 += __shfl_xor(rs2, 16);
        rs2 += __shfl_xor(rs2, 32);
        ll = ll * sfu + rs2;
        mm = mn;

        float sfq[4];
#pragma unroll
        for (int jj = 0; jj < 4; jj++) sfq[jj] = __shfl(sfu, g * 4 + jj);
#pragma unroll
        for (int ni = 0; ni < 4; ni++)
#pragma unroll
            for (int jj = 0; jj < 4; jj++) acc[ni][jj] *= sfq[jj];

#pragma unroll
        for (int tn = 0; tn < 4; tn++) {
            unsigned lo, hi;
            asm("v_cvt_pk_bf16_f32 %0, %1, %2" : "=v"(lo) : "v"(p[tn][0]), "v"(p[tn][1]));
            asm("v_cvt_pk_bf16_f32 %0, %1, %2" : "=v"(hi) : "v"(p[tn][2]), "v"(p[tn][3]));
            unsigned long long pk = (unsigned long long)lo | ((unsigned long long)hi << 32);
            int off = (li * 128 + tn * 32 + g * 8) ^ ((li & 7) << 4);
            *(unsigned long long*)(Pw + off) = pk;
        }
#pragma unroll
        for (int kt = 0; kt < 2; kt++) {
            int roff = (li * 128 + kt * 64 + g * 16) ^ ((li & 7) << 4);
            short8 ap = *(const short8*)(Pw + roff);
#pragma unroll
            for (int ni = 0; ni < 4; ni++) {
                int dk = ni * 16 + li;
                int vb = dk * 128 + ((((kt * 4 + g) << 4)) ^ ((dk & 7) << 4));
                short8 bv = *(const short8*)(Vsc + vb);
                acc[ni] = mfma16(ap, bv, acc[ni]);
            }
        }
        __syncthreads();
    }
    float inv = 1.f / ll;
    float invq[4];
#pragma unroll
    for (int jj = 0; jj < 4; jj++) invq[jj] = __shfl(inv, g * 4 + jj);
#pragma unroll
    for (int ni = 0; ni < 4; ni++)
#pragma unroll
        for (int jj = 0; jj < 4; jj++) {
            int row = b*Sv + qr0 + g*4 + jj;
            int col = h*DKv + ni*16 + li;
            Z[(size_t)row * Dv + col] = f2bf(acc[ni][jj] * invq[jj]);
        }
}

extern "C" void kernel_launch(void* const* d_in, const int* in_sizes, int n_in,
                              void* d_out, int out_size, void* d_ws, size_t ws_size,
                              hipStream_t stream) {
    const float* x  = (const float*)d_in[0];
    const float* Wq = (const float*)d_in[1];
    const float* Wk = (const float*)d_in[2];
    const float* Wv = (const float*)d_in[3];
    const float* W  = (const float*)d_in[4];
    float* out = (float*)d_out;

    short* xh   = (short*)d_ws;
    short* xl   = xh   + (size_t)Mv * Dv;
    short* Wh   = xl   + (size_t)Mv * Dv;
    short* Wl   = Wh   + (size_t)NQKV * Dv;
    short* W2T  = Wl   + (size_t)NQKV * Dv;
    short* QKVh = W2T  + (size_t)Dv * Dv;
    short* QKVl = QKVh + (size_t)Mv * NQKV;
    short* Vt   = QKVl + (size_t)Mv * NQK;
    short* Zb   = Vt   + (size_t)Bv*Hv*DKv * Sv;

    prep_kernel<<<dim3(3648), 256, 0, stream>>>(x, Wq, Wk, Wv, W, xh, xl, Wh, Wl, W2T);
    gemm_qk_kernel<<<dim3((NQK/128) * (Mv/128)), 256, 0, stream>>>(xh, xl, Wh, Wl, QKVh, QKVl);
    gemm_v_kernel<<<dim3((Dv/128) * (Mv/128)), 256, 0, stream>>>(xh, Wh, Vt);
    attn_kernel<<<dim3(768), 512, 0, stream>>>(QKVh, QKVl, Vt, Zb);
    gemm2_kernel<<<dim3((Dv/128) * (Mv/128)), 256, 0, stream>>>(Zb, W2T, out);
}

// Round 20
// 186.698 us; speedup vs baseline: 1.0555x; 1.0555x over previous
//
#include <hip/hip_runtime.h>

#define Bv 8
#define Sv 1024
#define Dv 768
#define Hv 12
#define DKv 64
#define Mv (Bv*Sv)          // 8192
#define NQKV (3*Hv*DKv)     // 2304
#define NQK (2*Hv*DKv)      // 1536

typedef __attribute__((ext_vector_type(8))) short short8;
typedef __attribute__((ext_vector_type(4))) short short4v;
typedef __attribute__((ext_vector_type(4))) float f32x4;

__device__ __forceinline__ short f2bf(float f) {
    unsigned u = __builtin_bit_cast(unsigned, f);
    u += 0x7fffu + ((u >> 16) & 1u);
    return (short)(u >> 16);
}
__device__ __forceinline__ float bf2f(short h) {
    return __builtin_bit_cast(float, (unsigned)(unsigned short)h << 16);
}

__device__ __forceinline__ f32x4 mfma16(short8 a, short8 b, f32x4 c) {
    return __builtin_amdgcn_mfma_f32_16x16x32_bf16(a, b, c, 0, 0, 0);
}

__device__ __forceinline__ void gload16(const short* g, const short* l) {
    __builtin_amdgcn_global_load_lds(
        (const __attribute__((address_space(1))) unsigned int*)g,
        (__attribute__((address_space(3))) unsigned int*)(short*)l, 16, 0, 0);
}

// ---------------- fused prep: split x | pack Wqkv hi/lo (Wq pre-scaled 1/8) | W^T ----------------
// blocks [0,3072): split_x; [3072,3504): pack; [3504,3648): transpose W.
__global__ __launch_bounds__(256) void prep_kernel(const float* __restrict__ x,
                                                   const float* __restrict__ Wq,
                                                   const float* __restrict__ Wk,
                                                   const float* __restrict__ Wv,
                                                   const float* __restrict__ W,
                                                   short* __restrict__ xh, short* __restrict__ xl,
                                                   short* __restrict__ Wh, short* __restrict__ Wl,
                                                   short* __restrict__ W2T) {
    __shared__ float lds[64][65];
    int bid = blockIdx.x;
    int t = threadIdx.x;
    if (bid < 3072) {
        int idx = bid * 256 + t;
        const float4* f = (const float4*)x + (size_t)idx * 2;
        float4 a = f[0], b = f[1];
        float v[8] = {a.x,a.y,a.z,a.w,b.x,b.y,b.z,b.w};
        short8 oh, ol;
#pragma unroll
        for (int k = 0; k < 8; k++) {
            short hi = f2bf(v[k]);
            oh[k] = hi;
            ol[k] = f2bf(v[k] - bf2f(hi));
        }
        *((short8*)xh + idx) = oh;
        *((short8*)xl + idx) = ol;
    } else if (bid < 3504) {
        int idx = bid - 3072;
        int dt = idx % 12, h = (idx / 12) % 12, p = idx / 144;
        const float* S = (p == 0 ? Wq : (p == 1 ? Wk : Wv)) + (size_t)h * Dv * DKv;
        float sc = (p == 0) ? 0.125f : 1.0f;
        int d0 = dt * 64;
#pragma unroll
        for (int i = 0; i < 4; i++) {
            int v = t + i * 256;
            int r = v >> 4, c4 = v & 15;
            float4 f = *(const float4*)&S[(size_t)(d0 + r) * DKv + c4 * 4];
            lds[r][c4*4+0] = f.x; lds[r][c4*4+1] = f.y; lds[r][c4*4+2] = f.z; lds[r][c4*4+3] = f.w;
        }
        __syncthreads();
#pragma unroll
        for (int i = 0; i < 2; i++) {
            int v = t + i * 256;
            int kk = v >> 3, dl0 = (v & 7) * 8;
            short8 oh, ol;
#pragma unroll
            for (int k = 0; k < 8; k++) {
                float f = lds[dl0 + k][kk] * sc;
                short hi = f2bf(f);
                oh[k] = hi;
                ol[k] = f2bf(f - bf2f(hi));
            }
            size_t base = (size_t)(p*768 + h*64 + kk) * Dv + d0 + dl0;
            *(short8*)&Wh[base] = oh;
            if (p < 2) *(short8*)&Wl[base] = ol;
        }
    } else {
        int idx = bid - 3504;
        int c0 = (idx % 12) * 64, r0 = (idx / 12) * 64;
#pragma unroll
        for (int i = 0; i < 4; i++) {
            int v = t + i * 256;
            int r = v >> 4, c4 = v & 15;
            float4 f = *(const float4*)&W[(size_t)(r0 + r) * Dv + c0 + c4 * 4];
            lds[r][c4*4+0] = f.x; lds[r][c4*4+1] = f.y; lds[r][c4*4+2] = f.z; lds[r][c4*4+3] = f.w;
        }
        __syncthreads();
#pragma unroll
        for (int i = 0; i < 2; i++) {
            int v = t + i * 256;
            int oc = v >> 3, rl0 = (v & 7) * 8;
            short8 o;
#pragma unroll
            for (int k = 0; k < 8; k++) o[k] = f2bf(lds[rl0 + k][oc]);
            *(short8*)&W2T[(size_t)(c0 + oc) * Dv + r0 + rl0] = o;
        }
    }
}

// XCD-affinity block swizzle for 1D grids over (x:NX, y:64)
__device__ __forceinline__ void swz_xy(int n, int& xbl, int& ybl) {
    int cx = n & 7, k = n >> 3;
    ybl = cx + 8 * (k & 7);
    xbl = k >> 3;
}

// ---------------- GEMM1: merged-segment split GEMM, 2 buffers + counted vmcnt ----------------
// QK blocks: phase 1 (t<24): stage {xh,Wh,Wl} (6 loads), 32 MFMA (xh.Wh + xh.Wl);
//            phase 2 (t<48): stage {xl,Wh}   (4 loads), 16 MFMA (xl.Wh).
// V blocks: 24 steps of {xh,Wh}, 16 MFMA; write Vt transposed directly.
__global__ __launch_bounds__(256, 3) void gemm1_kernel(const short* __restrict__ xh,
                                                       const short* __restrict__ xl,
                                                       const short* __restrict__ Wh,
                                                       const short* __restrict__ Wl,
                                                       short* __restrict__ QKVh,
                                                       short* __restrict__ QKVl,
                                                       short* __restrict__ Vt) {
    int xbl, ybl;
    swz_xy(blockIdx.x, xbl, ybl);
    int m0 = ybl * 128, n0 = xbl * 128;
    bool isv = (n0 >= NQK);
    int KT = isv ? 24 : 48;
    __shared__ __align__(16) short lA[2][4096];
    __shared__ __align__(16) short lBh[2][4096];
    __shared__ __align__(16) short lBl[2][4096];
    int tid = threadIdx.x, lane = tid & 63, w = tid >> 6;
    int wr = w >> 1, wc = w & 1;
    int li = lane & 15, g = lane >> 4;
    f32x4 zero = {0.f, 0.f, 0.f, 0.f};
    f32x4 acc[4][4];
#pragma unroll
    for (int i = 0; i < 4; i++)
#pragma unroll
        for (int j = 0; j < 4; j++) acc[i][j] = zero;

    int e0 = tid * 8;
    int sr0 = e0 >> 5;
    int sc0 = ((e0 >> 3) & 3) ^ ((sr0 >> 1) & 3);
    int sr1 = sr0 + 64;
    int sc1 = ((e0 >> 3) & 3) ^ ((sr1 >> 1) & 3);

    auto stage = [&](int t, int buf) {
        if (isv) {
            int kk = t * 32;
            gload16(xh + (size_t)(m0 + sr0) * Dv + kk + sc0 * 8, &lA[buf][w * 512]);
            gload16(Wh + (size_t)(n0 + sr0) * Dv + kk + sc0 * 8, &lBh[buf][w * 512]);
            gload16(xh + (size_t)(m0 + sr1) * Dv + kk + sc1 * 8, &lA[buf][2048 + w * 512]);
            gload16(Wh + (size_t)(n0 + sr1) * Dv + kk + sc1 * 8, &lBh[buf][2048 + w * 512]);
        } else if (t < 24) {
            int kk = t * 32;
            gload16(xh + (size_t)(m0 + sr0) * Dv + kk + sc0 * 8, &lA[buf][w * 512]);
            gload16(Wh + (size_t)(n0 + sr0) * Dv + kk + sc0 * 8, &lBh[buf][w * 512]);
            gload16(Wl + (size_t)(n0 + sr0) * Dv + kk + sc0 * 8, &lBl[buf][w * 512]);
            gload16(xh + (size_t)(m0 + sr1) * Dv + kk + sc1 * 8, &lA[buf][2048 + w * 512]);
            gload16(Wh + (size_t)(n0 + sr1) * Dv + kk + sc1 * 8, &lBh[buf][2048 + w * 512]);
            gload16(Wl + (size_t)(n0 + sr1) * Dv + kk + sc1 * 8, &lBl[buf][2048 + w * 512]);
        } else {
            int kk = (t - 24) * 32;
            gload16(xl + (size_t)(m0 + sr0) * Dv + kk + sc0 * 8, &lA[buf][w * 512]);
            gload16(Wh + (size_t)(n0 + sr0) * Dv + kk + sc0 * 8, &lBh[buf][w * 512]);
            gload16(xl + (size_t)(m0 + sr1) * Dv + kk + sc1 * 8, &lA[buf][2048 + w * 512]);
            gload16(Wh + (size_t)(n0 + sr1) * Dv + kk + sc1 * 8, &lBh[buf][2048 + w * 512]);
        }
    };

    stage(0, 0);
    stage(1, 1);

    for (int t = 0; t < KT; t++) {
        int cur = t & 1;
        if (t + 1 < KT) {
            if (!isv && t + 1 < 24) asm volatile("s_waitcnt vmcnt(6)" ::: "memory");
            else                    asm volatile("s_waitcnt vmcnt(4)" ::: "memory");
        } else {
            asm volatile("s_waitcnt vmcnt(0)" ::: "memory");
        }
        __builtin_amdgcn_s_barrier();          // tile t visible to all waves
        __builtin_amdgcn_sched_barrier(0);
        bool tri = (!isv) && (t < 24);
        short8 a[4], bbh[4], bbl[4];
#pragma unroll
        for (int mi = 0; mi < 4; mi++) {
            int row = wr*64 + mi*16 + li;
            a[mi] = *(const short8*)&lA[cur][row * 32 + ((g ^ ((row >> 1) & 3)) << 3)];
        }
#pragma unroll
        for (int ni = 0; ni < 4; ni++) {
            int row = wc*64 + ni*16 + li;
            bbh[ni] = *(const short8*)&lBh[cur][row * 32 + ((g ^ ((row >> 1) & 3)) << 3)];
        }
        if (tri) {
#pragma unroll
            for (int ni = 0; ni < 4; ni++) {
                int row = wc*64 + ni*16 + li;
                bbl[ni] = *(const short8*)&lBl[cur][row * 32 + ((g ^ ((row >> 1) & 3)) << 3)];
            }
        }
#pragma unroll
        for (int mi = 0; mi < 4; mi++)
#pragma unroll
            for (int ni = 0; ni < 4; ni++)
                acc[mi][ni] = mfma16(a[mi], bbh[ni], acc[mi][ni]);
        if (tri) {
#pragma unroll
            for (int mi = 0; mi < 4; mi++)
#pragma unroll
                for (int ni = 0; ni < 4; ni++)
                    acc[mi][ni] = mfma16(a[mi], bbl[ni], acc[mi][ni]);
        }
        __builtin_amdgcn_sched_barrier(0);     // ds_reads retired above this point
        __builtin_amdgcn_s_barrier();          // all waves done reading buf[cur]
        __builtin_amdgcn_sched_barrier(0);
        if (t + 2 < KT) stage(t + 2, cur);     // safe: buf[cur] dead for everyone
    }
    if (isv) {
        // write Vt[(bh*64+dk)][s] directly (transposed epilogue, short4 in s)
#pragma unroll
        for (int mi = 0; mi < 4; mi++)
#pragma unroll
            for (int ni = 0; ni < 4; ni++) {
                int vcol = n0 + wc*64 + ni*16 + li - NQK;   // 0..767
                int h = vcol >> 6, dk = vcol & 63;
                int row0 = m0 + wr*64 + mi*16 + g*4;
                int b = row0 >> 10, s0 = row0 & 1023;
                short4v v4;
                v4[0] = f2bf(acc[mi][ni][0]); v4[1] = f2bf(acc[mi][ni][1]);
                v4[2] = f2bf(acc[mi][ni][2]); v4[3] = f2bf(acc[mi][ni][3]);
                *(short4v*)&Vt[(size_t)((b*Hv + h)*64 + dk) * Sv + s0] = v4;
            }
    } else {
#pragma unroll
        for (int mi = 0; mi < 4; mi++)
#pragma unroll
            for (int ni = 0; ni < 4; ni++)
#pragma unroll
                for (int j = 0; j < 4; j++) {
                    int row = m0 + wr*64 + mi*16 + g*4 + j;
                    int col = n0 + wc*64 + ni*16 + li;
                    float v = acc[mi][ni][j];
                    short hi = f2bf(v);
                    QKVh[(size_t)row * NQKV + col] = hi;
                    QKVl[(size_t)row * NQK + col] = f2bf(v - bf2f(hi));
                }
    }
}

// ---------------- GEMM2: out(f32) = Zb @ W2T^T, counted-vmcnt loop ----------------
__global__ __launch_bounds__(256, 4) void gemm2_kernel(const short* __restrict__ A,
                                                       const short* __restrict__ Bt,
                                                       float* __restrict__ C) {
    int xbl, ybl;
    swz_xy(blockIdx.x, xbl, ybl);
    int m0 = ybl * 128, n0 = xbl * 128;
    __shared__ __align__(16) short lA[2][4096];
    __shared__ __align__(16) short lB[2][4096];
    int tid = threadIdx.x, lane = tid & 63, w = tid >> 6;
    int wr = w >> 1, wc = w & 1;
    int li = lane & 15, g = lane >> 4;
    f32x4 zero = {0.f, 0.f, 0.f, 0.f};
    f32x4 acc[4][4];
#pragma unroll
    for (int i = 0; i < 4; i++)
#pragma unroll
        for (int j = 0; j < 4; j++) acc[i][j] = zero;

    int e0 = tid * 8;
    int sr0 = e0 >> 5;
    int sc0 = ((e0 >> 3) & 3) ^ ((sr0 >> 1) & 3);
    int sr1 = sr0 + 64;
    int sc1 = ((e0 >> 3) & 3) ^ ((sr1 >> 1) & 3);

    auto stage = [&](int t, int buf) {
        int kk = t * 32;
        gload16(A  + (size_t)(m0 + sr0) * Dv + kk + sc0 * 8, &lA[buf][w * 512]);
        gload16(Bt + (size_t)(n0 + sr0) * Dv + kk + sc0 * 8, &lB[buf][w * 512]);
        gload16(A  + (size_t)(m0 + sr1) * Dv + kk + sc1 * 8, &lA[buf][2048 + w * 512]);
        gload16(Bt + (size_t)(n0 + sr1) * Dv + kk + sc1 * 8, &lB[buf][2048 + w * 512]);
    };

    stage(0, 0);
    stage(1, 1);

    for (int t = 0; t < 24; t++) {
        int cur = t & 1;
        if (t + 1 < 24) asm volatile("s_waitcnt vmcnt(4)" ::: "memory");
        else            asm volatile("s_waitcnt vmcnt(0)" ::: "memory");
        __builtin_amdgcn_s_barrier();
        __builtin_amdgcn_sched_barrier(0);
        short8 a[4], bb[4];
#pragma unroll
        for (int mi = 0; mi < 4; mi++) {
            int row = wr*64 + mi*16 + li;
            a[mi] = *(const short8*)&lA[cur][row * 32 + ((g ^ ((row >> 1) & 3)) << 3)];
        }
#pragma unroll
        for (int ni = 0; ni < 4; ni++) {
            int row = wc*64 + ni*16 + li;
            bb[ni] = *(const short8*)&lB[cur][row * 32 + ((g ^ ((row >> 1) & 3)) << 3)];
        }
#pragma unroll
        for (int mi = 0; mi < 4; mi++)
#pragma unroll
            for (int ni = 0; ni < 4; ni++)
                acc[mi][ni] = mfma16(a[mi], bb[ni], acc[mi][ni]);
        __builtin_amdgcn_sched_barrier(0);
        __builtin_amdgcn_s_barrier();
        __builtin_amdgcn_sched_barrier(0);
        if (t + 2 < 24) stage(t + 2, cur);
    }
#pragma unroll
    for (int mi = 0; mi < 4; mi++)
#pragma unroll
        for (int ni = 0; ni < 4; ni++)
#pragma unroll
            for (int j = 0; j < 4; j++) {
                int row = m0 + wr*64 + mi*16 + g*4 + j;
                int col = n0 + wc*64 + ni*16 + li;
                C[(size_t)row * Dv + col] = acc[mi][ni][j];
            }
}

// ---------------- flash attention ((512,6), no spills) ----------------
__global__ __launch_bounds__(512, 6) void attn_kernel(const short* __restrict__ QKVh,
                                                      const short* __restrict__ QKVl,
                                                      const short* __restrict__ Vt,
                                                      short* __restrict__ Z) {
    int n = blockIdx.x;
    int j2 = n >> 3;
    int bh = (n & 7) + 8 * (j2 >> 3);
    int qb = j2 & 7;
    int b = bh / Hv, h = bh % Hv;
    int tid = threadIdx.x, lane = tid & 63, w = tid >> 6;
    int li = lane & 15, g = lane >> 4;

    __shared__ __align__(16) short Kh[64 * 64];
    __shared__ __align__(16) short Kl[64 * 64];
    __shared__ __align__(16) short Vs[64 * 64];
    __shared__ __align__(16) short P[8][1024];
    char* Pw = (char*)&P[w][0];
    const char* Khc = (const char*)Kh;
    const char* Klc = (const char*)Kl;
    const char* Vsc = (const char*)Vs;

    int qr0 = qb * 128 + w * 16;
    const short* qhr = QKVh + (size_t)(b*Sv + qr0 + li) * NQKV + h * DKv;
    const short* qlr = QKVl + (size_t)(b*Sv + qr0 + li) * NQK  + h * DKv;
    short8 qh0 = *(const short8*)(qhr + g * 8);
    short8 qh1 = *(const short8*)(qhr + 32 + g * 8);
    short8 ql0 = *(const short8*)(qlr + g * 8);
    short8 ql1 = *(const short8*)(qlr + 32 + g * 8);

    const short* Khb = QKVh + (size_t)(b*Sv) * NQKV + Hv*DKv + h*DKv;
    const short* Klb = QKVl + (size_t)(b*Sv) * NQK  + Hv*DKv + h*DKv;
    const short* Vbase = Vt + (size_t)(bh * 64) * Sv;

    int srow = w * 8 + (lane >> 3);
    int scs  = (lane & 7) ^ (srow & 7);

    float mm = -1e30f, ll = 0.f;
    f32x4 zero = {0.f, 0.f, 0.f, 0.f};
    f32x4 acc[4];
#pragma unroll
    for (int ni = 0; ni < 4; ni++) acc[ni] = zero;

    for (int t = 0; t < 16; t++) {
        int t0 = t * 64;
        gload16(Khb + (size_t)(t0 + srow) * NQKV + scs * 8, &Kh[w * 512]);
        gload16(Klb + (size_t)(t0 + srow) * NQK  + scs * 8, &Kl[w * 512]);
        gload16(Vbase + (size_t)srow * Sv + t0 + scs * 8,   &Vs[w * 512]);
        __syncthreads();

        f32x4 s[4];
#pragma unroll
        for (int tn = 0; tn < 4; tn++) {
            int row = tn * 16 + li;
            int rb = row * 128, rs = (row & 7) << 4;
            short8 kh0 = *(const short8*)(Khc + rb + ((g << 4) ^ rs));
            short8 kh1 = *(const short8*)(Khc + rb + ((64 + (g << 4)) ^ rs));
            short8 kl0 = *(const short8*)(Klc + rb + ((g << 4) ^ rs));
            short8 kl1 = *(const short8*)(Klc + rb + ((64 + (g << 4)) ^ rs));
            f32x4 z = mfma16(kh0, qh0, zero);
            z = mfma16(kh1, qh1, z);
            z = mfma16(kl0, qh0, z);
            z = mfma16(kl1, qh1, z);
            z = mfma16(kh0, ql0, z);
            z = mfma16(kh1, ql1, z);
            s[tn] = z;
        }
        float rm = s[0][0];
#pragma unroll
        for (int tn = 0; tn < 4; tn++)
#pragma unroll
            for (int jj = 0; jj < 4; jj++) rm = fmaxf(rm, s[tn][jj]);
        rm = fmaxf(rm, __shfl_xor(rm, 16));
        rm = fmaxf(rm, __shfl_xor(rm, 32));
        float mn = fmaxf(mm, rm);
        float sfu = __expf(mm - mn);
        float p[4][4];
        float rs2 = 0.f;
#pragma unroll
        for (int tn = 0; tn < 4; tn++)
#pragma unroll
            for (int jj = 0; jj < 4; jj++) { p[tn][jj] = __expf(s[tn][jj] - mn); rs2 += p[tn][jj]; }
        rs2 += __shfl_xor(rs2, 16);
        rs2 += __shfl_xor(rs2, 32);
        ll = ll * sfu + rs2;
        mm = mn;

        float sfq[4];
#pragma unroll
        for (int jj = 0; jj < 4; jj++) sfq[jj] = __shfl(sfu, g * 4 + jj);
#pragma unroll
        for (int ni = 0; ni < 4; ni++)
#pragma unroll
            for (int jj = 0; jj < 4; jj++) acc[ni][jj] *= sfq[jj];

#pragma unroll
        for (int tn = 0; tn < 4; tn++) {
            unsigned lo, hi;
            asm("v_cvt_pk_bf16_f32 %0, %1, %2" : "=v"(lo) : "v"(p[tn][0]), "v"(p[tn][1]));
            asm("v_cvt_pk_bf16_f32 %0, %1, %2" : "=v"(hi) : "v"(p[tn][2]), "v"(p[tn][3]));
            unsigned long long pk = (unsigned long long)lo | ((unsigned long long)hi << 32);
            int off = (li * 128 + tn * 32 + g * 8) ^ ((li & 7) << 4);
            *(unsigned long long*)(Pw + off) = pk;
        }
#pragma unroll
        for (int kt = 0; kt < 2; kt++) {
            int roff = (li * 128 + kt * 64 + g * 16) ^ ((li & 7) << 4);
            short8 ap = *(const short8*)(Pw + roff);
#pragma unroll
            for (int ni = 0; ni < 4; ni++) {
                int dk = ni * 16 + li;
                int vb = dk * 128 + ((((kt * 4 + g) << 4)) ^ ((dk & 7) << 4));
                short8 bv = *(const short8*)(Vsc + vb);
                acc[ni] = mfma16(ap, bv, acc[ni]);
            }
        }
        __syncthreads();
    }
    float inv = 1.f / ll;
    float invq[4];
#pragma unroll
    for (int jj = 0; jj < 4; jj++) invq[jj] = __shfl(inv, g * 4 + jj);
#pragma unroll
    for (int ni = 0; ni < 4; ni++)
#pragma unroll
        for (int jj = 0; jj < 4; jj++) {
            int row = b*Sv + qr0 + g*4 + jj;
            int col = h*DKv + ni*16 + li;
            Z[(size_t)row * Dv + col] = f2bf(acc[ni][jj] * invq[jj]);
        }
}

extern "C" void kernel_launch(void* const* d_in, const int* in_sizes, int n_in,
                              void* d_out, int out_size, void* d_ws, size_t ws_size,
                              hipStream_t stream) {
    const float* x  = (const float*)d_in[0];
    const float* Wq = (const float*)d_in[1];
    const float* Wk = (const float*)d_in[2];
    const float* Wv = (const float*)d_in[3];
    const float* W  = (const float*)d_in[4];
    float* out = (float*)d_out;

    short* xh   = (short*)d_ws;
    short* xl   = xh   + (size_t)Mv * Dv;
    short* Wh   = xl   + (size_t)Mv * Dv;
    short* Wl   = Wh   + (size_t)NQKV * Dv;
    short* W2T  = Wl   + (size_t)NQKV * Dv;
    short* QKVh = W2T  + (size_t)Dv * Dv;
    short* QKVl = QKVh + (size_t)Mv * NQKV;
    short* Vt   = QKVl + (size_t)Mv * NQK;
    short* Zb   = Vt   + (size_t)Bv*Hv*DKv * Sv;

    prep_kernel<<<dim3(3648), 256, 0, stream>>>(x, Wq, Wk, Wv, W, xh, xl, Wh, Wl, W2T);
    gemm1_kernel<<<dim3((NQKV/128) * (Mv/128)), 256, 0, stream>>>(xh, xl, Wh, Wl, QKVh, QKVl, Vt);
    attn_kernel<<<dim3(768), 512, 0, stream>>>(QKVh, QKVl, Vt, Zb);
    gemm2_kernel<<<dim3((Dv/128) * (Mv/128)), 256, 0, stream>>>(Zb, W2T, out);
}